// Round 2
// baseline (250.271 us; speedup 1.0000x reference)
//
#include <hip/hip_runtime.h>
#include <cmath>

// Diagonal linear recurrence y[l][h] = exp(tau[h])*y[l-1][h] + x[l][h]
// L=16384, H=1024, fp32. Three-kernel chunked scan:
//   K1 li_ends:   per-chunk suffix-weighted sum e_c[h]   (reads x, writes 2MB)
//   K2 li_prefix: in-place exclusive carry prefix over e (tiny)
//   K3 li_out:    carry + local replay, writes y
// All memory ops are float4 (16B/lane) with explicit 8-deep load batching to
// force memory-level parallelism (R1 failure: compiler emitted vmcnt(0) per
// scalar load -> 1.0 TB/s latency-bound).

static constexpr int TC    = 32;   // rows per chunk  -> C = L/TC = 512
static constexpr int BATCH = 8;    // float4 loads in flight per thread

__global__ __launch_bounds__(256)
void li_ends(const float4* __restrict__ xv, const float4* __restrict__ tauv,
             float4* __restrict__ endsv, int HV) {
    const int t = threadIdx.x;            // float4 column (4 channels)
    const int c = blockIdx.x;             // chunk
    const float4 tv = tauv[t];
    const float lx = expf(tv.x), ly = expf(tv.y), lz = expf(tv.z), lw = expf(tv.w);

    const float4* xp = xv + (size_t)c * TC * HV + t;
    float4 s = make_float4(0.f, 0.f, 0.f, 0.f);
#pragma unroll
    for (int b = 0; b < TC / BATCH; ++b) {
        float4 buf[BATCH];
#pragma unroll
        for (int j = 0; j < BATCH; ++j)
            buf[j] = xp[(size_t)(b * BATCH + j) * HV];     // 8 independent loads
#pragma unroll
        for (int j = 0; j < BATCH; ++j) {
            s.x = fmaf(lx, s.x, buf[j].x);
            s.y = fmaf(ly, s.y, buf[j].y);
            s.z = fmaf(lz, s.z, buf[j].z);
            s.w = fmaf(lw, s.w, buf[j].w);
        }
    }
    endsv[(size_t)c * HV + t] = s;
}

// In-place: ends[c][h] (chunk aggregate) -> exclusive carry prefix with
// factor lamT = exp(TC*tau). 1024 threads, serial over C; loads independent.
__global__ __launch_bounds__(256)
void li_prefix(float* __restrict__ ends, const float* __restrict__ tau,
               int H, int C) {
    const int h = blockIdx.x * 256 + threadIdx.x;
    const float lamT = expf(tau[h] * (float)TC);
    float p = 0.f;
    for (int c = 0; c < C; ++c) {
        const size_t idx = (size_t)c * H + h;
        const float e = ends[idx];    // independent of chain; pipelines ahead
        ends[idx] = p;                // exclusive prefix = carry into chunk c
        p = fmaf(lamT, p, e);
    }
}

__global__ __launch_bounds__(256)
void li_out(const float4* __restrict__ xv, const float4* __restrict__ tauv,
            const float4* __restrict__ carryv, float4* __restrict__ yv, int HV) {
    const int t = threadIdx.x;
    const int c = blockIdx.x;
    const float4 tv = tauv[t];
    const float lx = expf(tv.x), ly = expf(tv.y), lz = expf(tv.z), lw = expf(tv.w);

    float4 s = carryv[(size_t)c * HV + t];   // carry into this chunk
    const size_t base = (size_t)c * TC * HV + t;
#pragma unroll
    for (int b = 0; b < TC / BATCH; ++b) {
        float4 buf[BATCH];
#pragma unroll
        for (int j = 0; j < BATCH; ++j)
            buf[j] = xv[base + (size_t)(b * BATCH + j) * HV];
#pragma unroll
        for (int j = 0; j < BATCH; ++j) {
            s.x = fmaf(lx, s.x, buf[j].x);
            s.y = fmaf(ly, s.y, buf[j].y);
            s.z = fmaf(lz, s.z, buf[j].z);
            s.w = fmaf(lw, s.w, buf[j].w);
            buf[j] = s;
        }
#pragma unroll
        for (int j = 0; j < BATCH; ++j)
            yv[base + (size_t)(b * BATCH + j) * HV] = buf[j];
    }
}

extern "C" void kernel_launch(void* const* d_in, const int* in_sizes, int n_in,
                              void* d_out, int out_size, void* d_ws, size_t ws_size,
                              hipStream_t stream) {
    const float* x   = (const float*)d_in[0];
    const float* tau = (const float*)d_in[1];
    float* y = (float*)d_out;

    const int H  = in_sizes[1];        // 1024
    const int L  = in_sizes[0] / H;    // 16384
    const int C  = L / TC;             // 512
    const int HV = H / 4;              // 256 float4 columns

    float* ends = (float*)d_ws;        // C*H floats = 2 MB scratch

    const float4* xv   = (const float4*)x;
    const float4* tauv = (const float4*)tau;
    float4*       yv   = (float4*)y;
    float4*       endsv = (float4*)ends;

    li_ends  <<<dim3(C),     dim3(256), 0, stream>>>(xv, tauv, endsv, HV);
    li_prefix<<<dim3(H/256), dim3(256), 0, stream>>>(ends, tau, H, C);
    li_out   <<<dim3(C),     dim3(256), 0, stream>>>(xv, tauv, (const float4*)endsv, yv, HV);
}

// Round 3
// 158.607 us; speedup vs baseline: 1.5779x; 1.5779x over previous
//
#include <hip/hip_runtime.h>
#include <cmath>

// Diagonal linear recurrence y[l][h] = exp(tau[h])*y[l-1][h] + x[l][h]
// L=16384, H=1024, fp32. Three-kernel chunked scan.
// R3: force memory-level parallelism with whole-chunk register arrays
// (R2 failure: li_prefix VGPR=4 -> compiler serialized loads -> 126 us).

static constexpr int PB = 16;   // prefix-kernel load batch

template <int TC>
__global__ __launch_bounds__(256)
void li_ends(const float4* __restrict__ xv, const float4* __restrict__ tauv,
             float4* __restrict__ endsv, int HV) {
    const int t = threadIdx.x;            // float4 column (4 channels)
    const int c = blockIdx.x;             // chunk
    const float4 tv = tauv[t];
    const float lx = expf(tv.x), ly = expf(tv.y), lz = expf(tv.z), lw = expf(tv.w);

    const float4* xp = xv + (size_t)c * TC * HV + t;
    float4 buf[TC];
#pragma unroll
    for (int i = 0; i < TC; ++i)
        buf[i] = xp[(size_t)i * HV];          // TC independent 16B loads in flight

    float4 s = make_float4(0.f, 0.f, 0.f, 0.f);
#pragma unroll
    for (int i = 0; i < TC; ++i) {
        s.x = fmaf(lx, s.x, buf[i].x);
        s.y = fmaf(ly, s.y, buf[i].y);
        s.z = fmaf(lz, s.z, buf[i].z);
        s.w = fmaf(lw, s.w, buf[i].w);
    }
    endsv[(size_t)c * HV + t] = s;
}

// In-place exclusive carry prefix over ends with factor lamT = exp(TC*tau).
// 1024 threads spread over 16 blocks; loads batched PB-deep.
template <int TC>
__global__ __launch_bounds__(64)
void li_prefix(float* __restrict__ ends, const float* __restrict__ tau,
               int H, int C) {
    const int h = blockIdx.x * 64 + threadIdx.x;
    const float lamT = expf(tau[h] * (float)TC);
    float p = 0.f;
    for (int c0 = 0; c0 < C; c0 += PB) {
        float e[PB];
#pragma unroll
        for (int j = 0; j < PB; ++j)
            e[j] = ends[(size_t)(c0 + j) * H + h];   // PB independent loads
#pragma unroll
        for (int j = 0; j < PB; ++j) {
            const float v = e[j];
            e[j] = p;                                 // exclusive prefix
            p = fmaf(lamT, p, v);
        }
#pragma unroll
        for (int j = 0; j < PB; ++j)
            ends[(size_t)(c0 + j) * H + h] = e[j];
    }
}

template <int TC>
__global__ __launch_bounds__(256)
void li_out(const float4* __restrict__ xv, const float4* __restrict__ tauv,
            const float4* __restrict__ carryv, float4* __restrict__ yv, int HV) {
    const int t = threadIdx.x;
    const int c = blockIdx.x;
    const float4 tv = tauv[t];
    const float lx = expf(tv.x), ly = expf(tv.y), lz = expf(tv.z), lw = expf(tv.w);

    const size_t base = (size_t)c * TC * HV + t;
    float4 buf[TC];
#pragma unroll
    for (int i = 0; i < TC; ++i)
        buf[i] = xv[base + (size_t)i * HV];

    float4 s = carryv[(size_t)c * HV + t];   // carry into this chunk
#pragma unroll
    for (int i = 0; i < TC; ++i) {
        s.x = fmaf(lx, s.x, buf[i].x);
        s.y = fmaf(ly, s.y, buf[i].y);
        s.z = fmaf(lz, s.z, buf[i].z);
        s.w = fmaf(lw, s.w, buf[i].w);
        buf[i] = s;
    }
#pragma unroll
    for (int i = 0; i < TC; ++i)
        yv[base + (size_t)i * HV] = buf[i];
}

template <int TC>
static void launch_all(const float* x, const float* tau, float* y, float* ends,
                       int H, int L, hipStream_t stream) {
    const int C  = L / TC;
    const int HV = H / 4;
    const float4* xv    = (const float4*)x;
    const float4* tauv  = (const float4*)tau;
    float4*       yv    = (float4*)y;
    float4*       endsv = (float4*)ends;

    li_ends<TC>  <<<dim3(C),    dim3(256), 0, stream>>>(xv, tauv, endsv, HV);
    li_prefix<TC><<<dim3(H/64), dim3(64),  0, stream>>>(ends, tau, H, C);
    li_out<TC>   <<<dim3(C),    dim3(256), 0, stream>>>(xv, tauv, (const float4*)endsv, yv, HV);
}

extern "C" void kernel_launch(void* const* d_in, const int* in_sizes, int n_in,
                              void* d_out, int out_size, void* d_ws, size_t ws_size,
                              hipStream_t stream) {
    const float* x   = (const float*)d_in[0];
    const float* tau = (const float*)d_in[1];
    float* y   = (float*)d_out;
    float* ends = (float*)d_ws;

    const int H = in_sizes[1];        // 1024
    const int L = in_sizes[0] / H;    // 16384

    const size_t need16 = (size_t)(L / 16) * H * sizeof(float);  // 4 MB
    if (ws_size >= need16)
        launch_all<16>(x, tau, y, ends, H, L, stream);
    else
        launch_all<32>(x, tau, y, ends, H, L, stream);
}